// Round 1
// baseline (324.819 us; speedup 1.0000x reference)
//
#include <hip/hip_runtime.h>
#include <hip/hip_bf16.h>

#define B_ 4
#define N_ 512
#define F_ 128
#define K_ 32

typedef __attribute__((ext_vector_type(8))) short short8;   // bf16x8 MFMA operand
typedef __attribute__((ext_vector_type(4))) float f32x4;    // MFMA accumulator

__device__ __forceinline__ short f2bf(float f) {
  unsigned u = __builtin_bit_cast(unsigned, f);
  u += 0x7fffu + ((u >> 16) & 1u);          // RNE
  return (short)(u >> 16);
}

__device__ __forceinline__ float sspf(float v) {
  // softplus(v) - ln2, numerically stable
  float t = __expf(-fabsf(v));
  return fmaxf(v, 0.f) + __logf(1.f + t) - 0.6931471805599453f;
}

// x[row][f] = sum_g emb[row][g] * Ww[f][g] + Wb[f]
__global__ void xw_kernel(const float* __restrict__ emb, const float* __restrict__ Ww,
                          const float* __restrict__ Wb, float* __restrict__ x) {
  __shared__ float erow[F_];
  int row = blockIdx.x;
  int f = threadIdx.x;
  erow[f] = emb[row * F_ + f];
  __syncthreads();
  const float4* w4 = (const float4*)(Ww + f * F_);
  float acc = 0.f;
#pragma unroll 8
  for (int g4 = 0; g4 < F_ / 4; ++g4) {
    float4 wv = w4[g4];
    acc = fmaf(erow[g4 * 4 + 0], wv.x, acc);
    acc = fmaf(erow[g4 * 4 + 1], wv.y, acc);
    acc = fmaf(erow[g4 * 4 + 2], wv.z, acc);
    acc = fmaf(erow[g4 * 4 + 3], wv.w, acc);
  }
  x[row * F_ + f] = acc + Wb[f];
}

__launch_bounds__(256, 2)
__global__ void schnet_kernel(const float* __restrict__ coords, const float* __restrict__ emb,
                              const float* __restrict__ w1, const float* __restrict__ b1,
                              const float* __restrict__ w2, const float* __restrict__ b2,
                              const float* __restrict__ x, float* __restrict__ out) {
  // w1t: [f][k], stride 40 shorts (80B rows -> conflict-free b128 reads, no swizzle)
  __shared__ __align__(16) short w1t[F_ * 40];
  // w2t: [f][g] bf16, XOR-swizzled: byte ^= (f&7)<<4
  __shared__ __align__(16) short w2t[F_ * F_];
  // h1:  [m][g] bf16, XOR-swizzled: byte ^= (m&7)<<4
  __shared__ __align__(16) short h1s[128 * F_];
  __shared__ float b1s[F_], b2s[F_];
  __shared__ float ored[2][F_];

  const int blk = blockIdx.x;
  const int b = blk >> 9, n = blk & 511;
  const int tid = threadIdx.x;
  const int lane = tid & 63, wave = tid >> 6;
  const int wr = wave >> 1, wc = wave & 1;
  const int l15 = lane & 15, lg = lane >> 4;

  // ---- stage weights (fp32 -> bf16, transposed) ----
  for (int idx = tid; idx < K_ * F_; idx += 256) {
    int f = idx & 127, k = idx >> 7;                 // coalesced read over f
    w1t[f * 40 + k] = f2bf(w1[k * F_ + f]);
  }
  for (int idx = tid; idx < F_ * F_; idx += 256) {
    int f = idx & 127, g = idx >> 7;
    int off = (f * 256 + ((g * 2) ^ ((f & 7) << 4))) >> 1;
    w2t[off] = f2bf(w2[g * F_ + f]);
  }
  if (tid < F_) {
    b1s[tid] = b1[tid];
    b2s[tid] = b2[tid];
    ored[0][tid] = 0.f;
    ored[1][tid] = 0.f;
  }
  const float cx = coords[(b * N_ + n) * 3 + 0];
  const float cy = coords[(b * N_ + n) * 3 + 1];
  const float cz = coords[(b * N_ + n) * 3 + 2];
  __syncthreads();

  // w1 B-fragments are m-tile invariant: load once
  short8 bw1[4];
#pragma unroll
  for (int nf = 0; nf < 4; ++nf)
    bw1[nf] = *(const short8*)&w1t[(wc * 64 + nf * 16 + l15) * 40 + lg * 8];

  const f32x4 zero4 = {0.f, 0.f, 0.f, 0.f};
  float outp[4] = {0.f, 0.f, 0.f, 0.f};

  for (int mt = 0; mt < 4; ++mt) {
    const int m0 = mt * 128;

    // ---- step B+C: rbf directly into A-fragments, then h1_pre = rbf @ w1 ----
    short8 arbf[4];
    f32x4 accC[4][4];
#pragma unroll
    for (int mf = 0; mf < 4; ++mf) {
      int rloc = wr * 64 + mf * 16 + l15;            // A-operand row = lane&15
      int m = m0 + rloc;
      const float* cm = coords + (b * N_ + m) * 3;
      float dx = cm[0] - cx, dy = cm[1] - cy, dz = cm[2] - cz;
      float d = sqrtf(fmaf(dx, dx, fmaf(dy, dy, fmaf(dz, dz, 1e-12f))));
      short8 a;
#pragma unroll
      for (int i = 0; i < 8; ++i) {
        float ck = (float)(lg * 8 + i) * (5.0f / 31.0f);
        float t = d - ck;
        a[i] = f2bf(__expf(-10.f * t * t));
      }
      arbf[mf] = a;
    }
#pragma unroll
    for (int mf = 0; mf < 4; ++mf)
#pragma unroll
      for (int nf = 0; nf < 4; ++nf)
        accC[mf][nf] = __builtin_amdgcn_mfma_f32_16x16x32_bf16(arbf[mf], bw1[nf], zero4, 0, 0, 0);

    __syncthreads();   // barrier A: previous iteration's h1 reads are done

    // ---- h1 = ssp(accC + b1) -> LDS (bf16, swizzled) ----
#pragma unroll
    for (int mf = 0; mf < 4; ++mf)
#pragma unroll
      for (int nf = 0; nf < 4; ++nf) {
        int col = wc * 64 + nf * 16 + l15;
        float bb = b1s[col];
#pragma unroll
        for (int j = 0; j < 4; ++j) {
          int row = wr * 64 + mf * 16 + lg * 4 + j;  // C/D: row = (lane>>4)*4 + j
          float v = sspf(accC[mf][nf][j] + bb);
          h1s[(row * 256 + ((col * 2) ^ ((row & 7) << 4))) >> 1] = f2bf(v);
        }
      }
    __syncthreads();   // barrier B: h1 tile complete

    // ---- step D: h2_pre = h1 @ w2 (K=128 -> 4 MFMA k-steps) ----
    f32x4 accD[4][4];
#pragma unroll
    for (int mf = 0; mf < 4; ++mf)
#pragma unroll
      for (int nf = 0; nf < 4; ++nf) accD[mf][nf] = zero4;

#pragma unroll
    for (int kk = 0; kk < 4; ++kk) {
      short8 af[4], bfr[4];
#pragma unroll
      for (int mf = 0; mf < 4; ++mf) {
        int rowA = wr * 64 + mf * 16 + l15;
        af[mf] = *(const short8*)((const char*)h1s +
                  rowA * 256 + ((kk * 64 + lg * 16) ^ ((rowA & 7) << 4)));
      }
#pragma unroll
      for (int nf = 0; nf < 4; ++nf) {
        int fcol = wc * 64 + nf * 16 + l15;
        bfr[nf] = *(const short8*)((const char*)w2t +
                  fcol * 256 + ((kk * 64 + lg * 16) ^ ((fcol & 7) << 4)));
      }
#pragma unroll
      for (int mf = 0; mf < 4; ++mf)
#pragma unroll
        for (int nf = 0; nf < 4; ++nf)
          accD[mf][nf] = __builtin_amdgcn_mfma_f32_16x16x32_bf16(af[mf], bfr[nf], accD[mf][nf], 0, 0, 0);
    }

    // ---- step E: Wf = ssp(accD + b2), mask diagonal, multiply x, accumulate columns ----
#pragma unroll
    for (int mf = 0; mf < 4; ++mf)
#pragma unroll
      for (int nf = 0; nf < 4; ++nf) {
        int fcol = wc * 64 + nf * 16 + l15;
        float bb = b2s[fcol];
#pragma unroll
        for (int j = 0; j < 4; ++j) {
          int row = wr * 64 + mf * 16 + lg * 4 + j;
          int m = m0 + row;
          float v = sspf(accD[mf][nf][j] + bb);
          float xv = x[(b * N_ + m) * F_ + fcol];
          outp[nf] += (m != n) ? v * xv : 0.f;
        }
      }
  }

  // ---- reduce partial column sums: over lane-groups (bits 4-5), then over wr via LDS ----
#pragma unroll
  for (int nf = 0; nf < 4; ++nf) {
    float v = outp[nf];
    v += __shfl_xor(v, 16);
    v += __shfl_xor(v, 32);
    if (lg == 0) ored[wr][wc * 64 + nf * 16 + l15] = v;
  }
  __syncthreads();
  if (tid < F_) {
    int o = (b * N_ + n) * F_ + tid;
    out[o] = emb[o] + ored[0][tid] + ored[1][tid];
  }
}

extern "C" void kernel_launch(void* const* d_in, const int* in_sizes, int n_in,
                              void* d_out, int out_size, void* d_ws, size_t ws_size,
                              hipStream_t stream) {
  const float* coords = (const float*)d_in[0];
  const float* emb    = (const float*)d_in[1];
  // d_in[2] = rbf_centers (linspace(0,5,32), recomputed inline)
  const float* w1 = (const float*)d_in[3];
  const float* b1 = (const float*)d_in[4];
  const float* w2 = (const float*)d_in[5];
  const float* b2 = (const float*)d_in[6];
  const float* Ww = (const float*)d_in[7];
  const float* Wb = (const float*)d_in[8];
  float* out = (float*)d_out;
  float* x   = (float*)d_ws;                 // B*N*F fp32 = 1 MiB scratch

  hipLaunchKernelGGL(xw_kernel, dim3(B_ * N_), dim3(F_), 0, stream, emb, Ww, Wb, x);
  hipLaunchKernelGGL(schnet_kernel, dim3(B_ * N_), dim3(256), 0, stream,
                     coords, emb, w1, b1, w2, b2, x, out);
}

// Round 2
// 220.834 us; speedup vs baseline: 1.4709x; 1.4709x over previous
//
#include <hip/hip_runtime.h>
#include <hip/hip_bf16.h>

#define B_ 4
#define N_ 512
#define F_ 128
#define K_ 32

typedef __attribute__((ext_vector_type(8))) short short8;   // bf16x8 MFMA operand
typedef __attribute__((ext_vector_type(4))) float f32x4;    // MFMA accumulator

// single-instruction f32->bf16 (RNE): v_cvt_pk_bf16_f32
__device__ __forceinline__ unsigned cvt_pk_bf16(float a, float b) {
  unsigned r;
  asm("v_cvt_pk_bf16_f32 %0, %1, %2" : "=v"(r) : "v"(a), "v"(b));
  return r;
}
__device__ __forceinline__ short f2bf1(float a) {
  return (short)cvt_pk_bf16(a, a);
}
__device__ __forceinline__ float exp2_hw(float x) {
  float r; asm("v_exp_f32 %0, %1" : "=v"(r) : "v"(x)); return r;
}
__device__ __forceinline__ float log2_hw(float x) {
  float r; asm("v_log_f32 %0, %1" : "=v"(r) : "v"(x)); return r;
}

// softplus(u) - ln2 = max(u,0) + ln2 * log2(0.5 + 0.5*exp2(-|u|*log2e))
__device__ __forceinline__ float sspb(float u) {
  float e = exp2_hw(__builtin_fabsf(u) * -1.4426950408889634f);
  float l = log2_hw(fmaf(e, 0.5f, 0.5f));
  return fmaf(l, 0.6931471805599453f, fmaxf(u, 0.f));
}

// x[row][f] = sum_g emb[row][g] * Ww[f][g] + Wb[f]
__global__ void xw_kernel(const float* __restrict__ emb, const float* __restrict__ Ww,
                          const float* __restrict__ Wb, float* __restrict__ x) {
  __shared__ float erow[F_];
  int row = blockIdx.x;
  int f = threadIdx.x;
  erow[f] = emb[row * F_ + f];
  __syncthreads();
  const float4* w4 = (const float4*)(Ww + f * F_);
  float acc = 0.f;
#pragma unroll 8
  for (int g4 = 0; g4 < F_ / 4; ++g4) {
    float4 wv = w4[g4];
    acc = fmaf(erow[g4 * 4 + 0], wv.x, acc);
    acc = fmaf(erow[g4 * 4 + 1], wv.y, acc);
    acc = fmaf(erow[g4 * 4 + 2], wv.z, acc);
    acc = fmaf(erow[g4 * 4 + 3], wv.w, acc);
  }
  x[row * F_ + f] = acc + Wb[f];
}

__launch_bounds__(512, 4)
__global__ void schnet_kernel(const float* __restrict__ coords, const float* __restrict__ emb,
                              const float* __restrict__ w1, const float* __restrict__ b1,
                              const float* __restrict__ w2, const float* __restrict__ b2,
                              const float* __restrict__ x, float* __restrict__ out) {
  // w1t: [f][k], stride 40 shorts (80B rows -> conflict-free b128 reads)
  __shared__ __align__(16) short w1t[F_ * 40];
  // w2t: [f][g] bf16, XOR-swizzled: byte ^= (f&7)<<4
  __shared__ __align__(16) short w2t[F_ * F_];
  // h1:  [m][g] bf16, XOR-swizzled: byte ^= (m&7)<<4
  __shared__ __align__(16) short h1s[128 * F_];
  __shared__ float b1s[F_], b2s[F_];
  __shared__ float ored[4][F_];

  const int blk = blockIdx.x;
  const int b = blk >> 9, n = blk & 511;
  const int tid = threadIdx.x;
  const int lane = tid & 63, wave = tid >> 6;     // 8 waves
  const int wr = wave >> 1, wc = wave & 1;        // 4 x 2 wave grid
  const int l15 = lane & 15, lg = lane >> 4;

  // ---- stage weights (fp32 -> bf16, transposed) ----
  for (int idx = tid; idx < K_ * F_; idx += 512) {
    int f = idx & 127, k = idx >> 7;
    w1t[f * 40 + k] = f2bf1(w1[k * F_ + f]);
  }
  for (int idx = tid; idx < F_ * F_; idx += 512) {
    int f = idx & 127, g = idx >> 7;
    int off = (f * 256 + ((g * 2) ^ ((f & 7) << 4))) >> 1;
    w2t[off] = f2bf1(w2[g * F_ + f]);
  }
  if (tid < F_) {
    b1s[tid] = b1[tid];
    b2s[tid] = b2[tid];
  }
  const float cx = coords[(b * N_ + n) * 3 + 0];
  const float cy = coords[(b * N_ + n) * 3 + 1];
  const float cz = coords[(b * N_ + n) * 3 + 2];
  __syncthreads();

  // per-lane column (g for layer1, f for layer2) is tile-invariant
  const int col = wc * 64 + l15;                  // + nf*16
  short8 bw1[4];
  float bb1[4], bb2[4];
#pragma unroll
  for (int nf = 0; nf < 4; ++nf) {
    bw1[nf] = *(const short8*)&w1t[(col + nf * 16) * 40 + lg * 8];
    bb1[nf] = b1s[col + nf * 16];
    bb2[nf] = b2s[col + nf * 16];
  }

  const f32x4 zero4 = {0.f, 0.f, 0.f, 0.f};
  float outp[4] = {0.f, 0.f, 0.f, 0.f};

  for (int mt = 0; mt < 4; ++mt) {
    const int m0 = mt * 128;

    // ---- rbf directly into A-fragments; h1_pre = rbf @ w1 ----
    short8 arbf[2];
    f32x4 accC[2][4];
#pragma unroll
    for (int mf = 0; mf < 2; ++mf) {
      int m = m0 + wr * 32 + mf * 16 + l15;       // A row = lane&15
      const float* cm = coords + (b * N_ + m) * 3;
      float dx = cm[0] - cx, dy = cm[1] - cy, dz = cm[2] - cz;
      float d = sqrtf(fmaf(dx, dx, fmaf(dy, dy, fmaf(dz, dz, 1e-12f))));
      unsigned pk[4];
#pragma unroll
      for (int p = 0; p < 4; ++p) {
        float t0 = d - (float)(lg * 8 + 2 * p) * (5.0f / 31.0f);
        float t1 = d - (float)(lg * 8 + 2 * p + 1) * (5.0f / 31.0f);
        float e0 = exp2_hw(t0 * t0 * -14.426950408889634f);
        float e1 = exp2_hw(t1 * t1 * -14.426950408889634f);
        pk[p] = cvt_pk_bf16(e0, e1);
      }
      arbf[mf] = *(short8*)pk;
    }
#pragma unroll
    for (int mf = 0; mf < 2; ++mf)
#pragma unroll
      for (int nf = 0; nf < 4; ++nf)
        accC[mf][nf] = __builtin_amdgcn_mfma_f32_16x16x32_bf16(arbf[mf], bw1[nf], zero4, 0, 0, 0);

    __syncthreads();   // previous tile's h1 reads complete

    // ---- h1 = ssp(accC + b1) -> LDS (bf16, swizzled) ----
#pragma unroll
    for (int mf = 0; mf < 2; ++mf)
#pragma unroll
      for (int nf = 0; nf < 4; ++nf) {
        int colB = (col + nf * 16) * 2;
#pragma unroll
        for (int j = 0; j < 4; ++j) {
          int row = wr * 32 + mf * 16 + lg * 4 + j;
          float v = sspb(accC[mf][nf][j] + bb1[nf]);
          *(short*)((char*)h1s + row * 256 + (colB ^ ((row & 7) << 4))) = f2bf1(v);
        }
      }
    __syncthreads();   // h1 tile complete

    // ---- h2_pre = h1 @ w2 (K=128 -> 4 k-steps) ----
    f32x4 accD[2][4];
#pragma unroll
    for (int mf = 0; mf < 2; ++mf)
#pragma unroll
      for (int nf = 0; nf < 4; ++nf) accD[mf][nf] = zero4;

#pragma unroll
    for (int kk = 0; kk < 4; ++kk) {
      short8 af[2], bfr[4];
#pragma unroll
      for (int mf = 0; mf < 2; ++mf) {
        int rowA = wr * 32 + mf * 16 + l15;
        af[mf] = *(const short8*)((const char*)h1s +
                  rowA * 256 + ((kk * 64 + lg * 16) ^ ((rowA & 7) << 4)));
      }
#pragma unroll
      for (int nf = 0; nf < 4; ++nf) {
        int fcol = col + nf * 16;
        bfr[nf] = *(const short8*)((const char*)w2t +
                  fcol * 256 + ((kk * 64 + lg * 16) ^ ((fcol & 7) << 4)));
      }
#pragma unroll
      for (int mf = 0; mf < 2; ++mf)
#pragma unroll
        for (int nf = 0; nf < 4; ++nf)
          accD[mf][nf] = __builtin_amdgcn_mfma_f32_16x16x32_bf16(af[mf], bfr[nf], accD[mf][nf], 0, 0, 0);
    }

    // ---- Wf = ssp(accD + b2), mask diagonal, multiply x, accumulate ----
#pragma unroll
    for (int mf = 0; mf < 2; ++mf)
#pragma unroll
      for (int nf = 0; nf < 4; ++nf) {
        int fcol = col + nf * 16;
        float xv[4], sv[4];
        int mbase = m0 + wr * 32 + mf * 16 + lg * 4;
#pragma unroll
        for (int j = 0; j < 4; ++j)
          xv[j] = x[(b * N_ + mbase + j) * F_ + fcol];
#pragma unroll
        for (int j = 0; j < 4; ++j)
          sv[j] = sspb(accD[mf][nf][j] + bb2[nf]);
#pragma unroll
        for (int j = 0; j < 4; ++j)
          outp[nf] += (mbase + j != n) ? sv[j] * xv[j] : 0.f;
      }
  }

  // ---- reduce column partials: lane-groups (bits 4-5) then the 4 wr waves ----
#pragma unroll
  for (int nf = 0; nf < 4; ++nf) {
    float v = outp[nf];
    v += __shfl_xor(v, 16);
    v += __shfl_xor(v, 32);
    if (lg == 0) ored[wr][col + nf * 16] = v;
  }
  __syncthreads();
  if (tid < F_) {
    int o = (b * N_ + n) * F_ + tid;
    out[o] = emb[o] + ored[0][tid] + ored[1][tid] + ored[2][tid] + ored[3][tid];
  }
}

extern "C" void kernel_launch(void* const* d_in, const int* in_sizes, int n_in,
                              void* d_out, int out_size, void* d_ws, size_t ws_size,
                              hipStream_t stream) {
  const float* coords = (const float*)d_in[0];
  const float* emb    = (const float*)d_in[1];
  // d_in[2] = rbf_centers (linspace(0,5,32), recomputed inline)
  const float* w1 = (const float*)d_in[3];
  const float* b1 = (const float*)d_in[4];
  const float* w2 = (const float*)d_in[5];
  const float* b2 = (const float*)d_in[6];
  const float* Ww = (const float*)d_in[7];
  const float* Wb = (const float*)d_in[8];
  float* out = (float*)d_out;
  float* x   = (float*)d_ws;                 // B*N*F fp32 = 1 MiB scratch

  hipLaunchKernelGGL(xw_kernel, dim3(B_ * N_), dim3(F_), 0, stream, emb, Ww, Wb, x);
  hipLaunchKernelGGL(schnet_kernel, dim3(B_ * N_), dim3(512), 0, stream,
                     coords, emb, w1, b1, w2, b2, x, out);
}